// Round 1
// baseline (128.334 us; speedup 1.0000x reference)
//
#include <hip/hip_runtime.h>

constexpr int kB  = 16;
constexpr int kN  = 1024;
constexpr int kE  = 16;
constexpr int kDI = 32;
constexpr int kDO = 32;

// ---------------------------------------------------------------------------
// apply_S: Y[b,n,:] = softmax_row(relu(emb[b] @ emb[b]^T)) @ V[b]
// grid = B * (N/32) blocks, 256 threads (4 waves).
// Each block: 32 rows. Thread owns 2 rows and 1/16 of the m-range.
// relu >= 0 and |dot| <~ 50  =>  exp without max-subtraction is safe in fp32.
// ---------------------------------------------------------------------------
__global__ __launch_bounds__(256) void apply_S(
    const float* __restrict__ emb,   // [B,N,16]
    const float* __restrict__ V,     // [B,N,32]
    float* __restrict__ Y)           // [B,N,32]
{
    __shared__ float emb_s[64][20];   // 64 m-rows x 16 (pad 20)
    __shared__ float v_s[64][36];     // 64 m-rows x 32 (pad 36)
    __shared__ float ob[32 * 32];     // output staging

    const int tid = threadIdx.x;
    const int w   = tid >> 6;        // wave 0..3
    const int l   = tid & 63;
    const int s   = l & 15;          // m-subset 0..15
    const int rp  = l >> 4;          // row-pair in wave 0..3

    const int blk      = blockIdx.x;
    const int b        = blk >> 5;           // 32 row-blocks per batch
    const int row_base = (blk & 31) << 5;

    const int r0 = (w << 3) + (rp << 1);     // local row (0..30, even)
    const float* embB = emb + (size_t)b * kN * kE;
    const float* vB   = V   + (size_t)b * kN * 32;

    // load the two query rows into registers (broadcast within 16-lane groups)
    float en0[16], en1[16];
    {
        const float4* p0 = (const float4*)(embB + (size_t)(row_base + r0) * kE);
        const float4* p1 = (const float4*)(embB + (size_t)(row_base + r0 + 1) * kE);
        #pragma unroll
        for (int j = 0; j < 4; ++j) {
            float4 a = p0[j], c = p1[j];
            en0[4*j+0]=a.x; en0[4*j+1]=a.y; en0[4*j+2]=a.z; en0[4*j+3]=a.w;
            en1[4*j+0]=c.x; en1[4*j+1]=c.y; en1[4*j+2]=c.z; en1[4*j+3]=c.w;
        }
    }

    float acc0[32], acc1[32];
    #pragma unroll
    for (int d = 0; d < 32; ++d) { acc0[d] = 0.f; acc1[d] = 0.f; }
    float L0 = 0.f, L1 = 0.f;

    for (int t = 0; t < 16; ++t) {
        const int m0 = t << 6;
        __syncthreads();
        // stage emb tile: 64x16 floats -> 1 float4/thread
        {
            int r = tid >> 2, c = (tid & 3) << 2;
            float4 a = *(const float4*)(embB + (size_t)(m0 + r) * kE + c);
            emb_s[r][c+0]=a.x; emb_s[r][c+1]=a.y; emb_s[r][c+2]=a.z; emb_s[r][c+3]=a.w;
        }
        // stage V tile: 64x32 floats -> 2 float4/thread
        #pragma unroll
        for (int q = 0; q < 2; ++q) {
            int f = q * 256 + tid;               // float4 index 0..511
            int r = f >> 3, c = (f & 7) << 2;
            float4 a = *(const float4*)(vB + (size_t)(m0 + r) * 32 + c);
            v_s[r][c+0]=a.x; v_s[r][c+1]=a.y; v_s[r][c+2]=a.z; v_s[r][c+3]=a.w;
        }
        __syncthreads();

        #pragma unroll
        for (int j = 0; j < 4; ++j) {
            const int ml = (j << 4) + s;
            float d0 = 0.f, d1 = 0.f;
            #pragma unroll
            for (int c = 0; c < 16; ++c) {
                float ev = emb_s[ml][c];
                d0 += en0[c] * ev;
                d1 += en1[c] * ev;
            }
            d0 = fmaxf(d0, 0.f); d1 = fmaxf(d1, 0.f);
            float p0 = __expf(d0), p1 = __expf(d1);
            L0 += p0; L1 += p1;
            #pragma unroll
            for (int d = 0; d < 32; ++d) {
                float vv = v_s[ml][d];
                acc0[d] += p0 * vv;
                acc1[d] += p1 * vv;
            }
        }
    }

    // reduce across the 16 m-subsets (lanes differing in bits 0..3)
    #pragma unroll
    for (int off = 1; off < 16; off <<= 1) {
        L0 += __shfl_xor(L0, off);
        L1 += __shfl_xor(L1, off);
        #pragma unroll
        for (int d = 0; d < 32; ++d) {
            acc0[d] += __shfl_xor(acc0[d], off);
            acc1[d] += __shfl_xor(acc1[d], off);
        }
    }

    __syncthreads();   // all v_s/emb_s reads done before reusing LDS phase
    if (s == 0) {
        float iL0 = 1.f / L0, iL1 = 1.f / L1;
        #pragma unroll
        for (int d = 0; d < 32; ++d) {
            ob[r0 * 32 + d]       = acc0[d] * iL0;
            ob[(r0 + 1) * 32 + d] = acc1[d] * iL1;
        }
    }
    __syncthreads();
    {
        // 32 rows x 32 cols = 256 float4, coalesced store
        float4 a = ((const float4*)ob)[tid];
        ((float4*)(Y + (size_t)(b * kN + row_base) * 32))[tid] = a;
    }
}

// ---------------------------------------------------------------------------
// final: out[n,o] = sum_e s[n,e] * ( bias[e,o] + sum_ki XG[n,ki]*W[e,ki/32,ki%32,o] )
// XG[n, k*32+i]: k=0 -> x, k=1 -> y1, k=2 -> 2*y2 - x
// GEMM tile: 32 nodes x 512 cols (col = e*32+o), K=96 in 3 chunks of 32.
// Thread = (rg = tid>>5 -> 4 rows, o = tid&31 -> 16 e-columns at fixed o).
// ---------------------------------------------------------------------------
__global__ __launch_bounds__(256) void final_gemm(
    const float* __restrict__ x,      // [B,N,32]
    const float* __restrict__ y1,
    const float* __restrict__ y2,
    const float* __restrict__ stock,  // [B,N,16]
    const float* __restrict__ Wp,     // [16,3,32,32]
    const float* __restrict__ bias,   // [16,32]
    float* __restrict__ out)          // [B,N,32]
{
    __shared__ float xg_s[32 * 96];
    __shared__ float w_s[32 * 512];
    __shared__ float s_s[32 * 16];

    const int tid    = threadIdx.x;
    const int row0_g = blockIdx.x << 5;   // flattened node base (b*N+n)
    const int rg     = tid >> 5;          // 0..7
    const int o      = tid & 31;

    // stage XG (32 x 96) and stock (32 x 16)
    for (int idx = tid; idx < 1024; idx += 256) {
        int r = idx >> 5, i = idx & 31;
        size_t g = (size_t)(row0_g + r) * 32 + i;
        float xv = x[g], y1v = y1[g], y2v = y2[g];
        xg_s[r * 96 + i]      = xv;
        xg_s[r * 96 + 32 + i] = y1v;
        xg_s[r * 96 + 64 + i] = 2.f * y2v - xv;
    }
    for (int idx = tid; idx < 512; idx += 256)
        s_s[idx] = stock[(size_t)row0_g * kE + idx];

    float bv[16];
    #pragma unroll
    for (int e = 0; e < 16; ++e) bv[e] = bias[e * 32 + o];

    float acc[4][16];
    #pragma unroll
    for (int j = 0; j < 4; ++j)
        #pragma unroll
        for (int e = 0; e < 16; ++e) acc[j][e] = 0.f;

    for (int ch = 0; ch < 3; ++ch) {
        __syncthreads();
        // stage W chunk: rows ki = ch*32..+31, cols 0..511 (col = e*32+oo)
        #pragma unroll
        for (int q = 0; q < 16; ++q) {
            int f4  = q * 256 + tid;
            int r   = f4 >> 7;          // 0..31 (kk)
            int c4  = f4 & 127;
            int col = c4 << 2;
            int e   = col >> 5;
            int oo  = col & 31;
            int ki  = ch * 32 + r;
            float4 a = *(const float4*)(Wp + (size_t)e * 3072 + (size_t)ki * 32 + oo);
            *(float4*)(&w_s[r * 512 + col]) = a;
        }
        __syncthreads();

        #pragma unroll
        for (int kk = 0; kk < 32; ++kk) {
            float xv[4];
            #pragma unroll
            for (int j = 0; j < 4; ++j)
                xv[j] = xg_s[(rg * 4 + j) * 96 + ch * 32 + kk];
            #pragma unroll
            for (int e = 0; e < 16; ++e) {
                float wv = w_s[kk * 512 + e * 32 + o];
                #pragma unroll
                for (int j = 0; j < 4; ++j)
                    acc[j][e] += xv[j] * wv;
            }
        }
    }

    #pragma unroll
    for (int j = 0; j < 4; ++j) {
        int r = rg * 4 + j;
        float sum = 0.f;
        #pragma unroll
        for (int e = 0; e < 16; ++e)
            sum += s_s[r * 16 + e] * (acc[j][e] + bv[e]);
        out[(size_t)(row0_g + r) * 32 + o] = sum;
    }
}

extern "C" void kernel_launch(void* const* d_in, const int* in_sizes, int n_in,
                              void* d_out, int out_size, void* d_ws, size_t ws_size,
                              hipStream_t stream) {
    const float* x     = (const float*)d_in[0];
    const float* aemb  = (const float*)d_in[1];
    const float* stock = (const float*)d_in[2];
    const float* Wp    = (const float*)d_in[3];
    const float* bias  = (const float*)d_in[4];
    float* out = (float*)d_out;

    float* y1 = (float*)d_ws;
    float* y2 = y1 + (size_t)kB * kN * 32;

    dim3 blk(256);
    apply_S<<<dim3(kB * (kN / 32)), blk, 0, stream>>>(aemb, x,  y1);
    apply_S<<<dim3(kB * (kN / 32)), blk, 0, stream>>>(aemb, y1, y2);
    final_gemm<<<dim3((kB * kN) / 32), blk, 0, stream>>>(x, y1, y2, stock, Wp, bias, out);
}